// Round 1
// baseline (11037.086 us; speedup 1.0000x reference)
//
#include <hip/hip_runtime.h>
#include <hip/hip_bf16.h>

#define H 1024
#define H3 3072
#define SEQ 2048
#define NB 64        // scan workgroups
#define SLICE 16     // h outputs per WG (H / NB)
#define NT 256

// workspace layout (floats)
#define GI_F   ((size_t)SEQ * H3)            // gi: 6,291,456 floats
#define HB_F   ((size_t)(SEQ + 1) * H)       // h history: 2,098,176 floats
#define FLAGS_W ((size_t)(SEQ + 1) * NB)     // flags: 131,136 words

// ---------------------------------------------------------------------------
// setup: h_buf[0] = hidden, flags[0][*] = 1 (ready), flags[t>=1][*] = 0
// ---------------------------------------------------------------------------
__global__ void setup_kernel(const float* __restrict__ hidden,
                             float* __restrict__ h_buf,
                             unsigned int* __restrict__ flags) {
  const int idx = blockIdx.x * NT + threadIdx.x;
  if (blockIdx.x == 0) {
    ((float4*)h_buf)[threadIdx.x] = ((const float4*)hidden)[threadIdx.x]; // 256*4 = 1024
    if (threadIdx.x < NB) flags[threadIdx.x] = 1u;
  }
  for (size_t i = (size_t)NB + idx; i < FLAGS_W; i += (size_t)NB * NT)
    flags[i] = 0u;
}

// ---------------------------------------------------------------------------
// gi[s][j] = b_ih[j] + sum_k emb[tok[s]][k] * w_ih[j][k]
// 64x64 tile, 16-wide k-blocks in LDS, 4x4 per thread, fp32
// ---------------------------------------------------------------------------
__global__ __launch_bounds__(NT) void gemm_gi(
    const int* __restrict__ tok, const float* __restrict__ emb,
    const float* __restrict__ w_ih, const float* __restrict__ b_ih,
    float* __restrict__ gi) {
  __shared__ float As[16][64];  // [k][s]
  __shared__ float Bs[16][64];  // [k][j]
  const int s0 = blockIdx.x * 64;
  const int j0 = blockIdx.y * 64;
  const int tid = threadIdx.x;
  const int tr = tid & 15, tc = tid >> 4;
  const int lr = tid >> 2, lc = (tid & 3) << 2;
  const float* arow = emb + (size_t)tok[s0 + lr] * H;
  const float* brow = w_ih + (size_t)(j0 + lr) * H;
  float acc[4][4] = {};
  for (int k0 = 0; k0 < H; k0 += 16) {
    float4 av = *(const float4*)(arow + k0 + lc);
    float4 bv = *(const float4*)(brow + k0 + lc);
    __syncthreads();
    As[lc + 0][lr] = av.x; As[lc + 1][lr] = av.y;
    As[lc + 2][lr] = av.z; As[lc + 3][lr] = av.w;
    Bs[lc + 0][lr] = bv.x; Bs[lc + 1][lr] = bv.y;
    Bs[lc + 2][lr] = bv.z; Bs[lc + 3][lr] = bv.w;
    __syncthreads();
#pragma unroll
    for (int k = 0; k < 16; ++k) {
      float4 a = *(const float4*)&As[k][tr << 2];
      float4 b = *(const float4*)&Bs[k][tc << 2];
      acc[0][0] += a.x * b.x; acc[0][1] += a.x * b.y; acc[0][2] += a.x * b.z; acc[0][3] += a.x * b.w;
      acc[1][0] += a.y * b.x; acc[1][1] += a.y * b.y; acc[1][2] += a.y * b.z; acc[1][3] += a.y * b.w;
      acc[2][0] += a.z * b.x; acc[2][1] += a.z * b.y; acc[2][2] += a.z * b.z; acc[2][3] += a.z * b.w;
      acc[3][0] += a.w * b.x; acc[3][1] += a.w * b.y; acc[3][2] += a.w * b.z; acc[3][3] += a.w * b.w;
    }
  }
#pragma unroll
  for (int mi = 0; mi < 4; ++mi) {
    float4 v;
    v.x = acc[mi][0] + b_ih[j0 + (tc << 2) + 0];
    v.y = acc[mi][1] + b_ih[j0 + (tc << 2) + 1];
    v.z = acc[mi][2] + b_ih[j0 + (tc << 2) + 2];
    v.w = acc[mi][3] + b_ih[j0 + (tc << 2) + 3];
    *(float4*)&gi[(size_t)(s0 + (tr << 2) + mi) * H3 + j0 + (tc << 2)] = v;
  }
}

// ---------------------------------------------------------------------------
// persistent GRU scan + output heads
// ---------------------------------------------------------------------------
__device__ __forceinline__ float sigmoid_f(float x) {
  return 1.0f / (1.0f + __expf(-x));
}
__device__ __forceinline__ float tanh_f(float x) {
  return 2.0f / (1.0f + __expf(-2.0f * x)) - 1.0f;  // saturates correctly
}
__device__ __forceinline__ float sel4_f(const float* a, int oi) {
  float x = (oi & 1) ? a[1] : a[0];
  float y = (oi & 1) ? a[3] : a[2];
  return (oi & 2) ? y : x;
}

__global__ __launch_bounds__(NT, 1) void scan_kernel(
    const float* __restrict__ w_hh, const float* __restrict__ b_hh,
    const float* __restrict__ w_mean, const float* __restrict__ b_mean,
    const float* __restrict__ w_std, const float* __restrict__ b_std,
    const float* __restrict__ gi, float* __restrict__ h_buf,
    unsigned int* __restrict__ flags, float* __restrict__ out) {
  __shared__ float h_lds[H];
  const int b = blockIdx.x;
  const int tid = threadIdx.x;
  const int wave = tid >> 6;
  const int lane = tid & 63;
  const int i_base = b * SLICE + wave * 4;   // this wave's 4 outputs
  const int oi = lane & 3;
  const int i_fin = i_base + oi;             // output finalized by lanes 0..3

  // --- w_hh rows for this wave, resident in VGPRs ---
  // wf[g][o][c] = w_hh[g*H + i_base+o][c*256 + lane*4 .. +3]
  float4 wf[3][4][4];
#pragma unroll
  for (int g = 0; g < 3; ++g)
#pragma unroll
    for (int o = 0; o < 4; ++o) {
      const float* row = w_hh + (size_t)(g * H + i_base + o) * H;
#pragma unroll
      for (int c = 0; c < 4; ++c)
        wf[g][o][c] = *(const float4*)(row + c * 256 + lane * 4);
    }
  const float bhr = b_hh[i_fin];
  const float bhz = b_hh[H + i_fin];
  const float bhn = b_hh[2 * H + i_fin];

  for (int t = 0; t < SEQ; ++t) {
    // issue gi loads early (hidden behind the flag poll)
    const size_t gbase = (size_t)t * H3;
    const float g_r = gi[gbase + i_fin];
    const float g_z = gi[gbase + H + i_fin];
    const float g_n = gi[gbase + 2 * H + i_fin];

    // wave 0: wait for all 64 producer slices, stage h_t into LDS
    if (wave == 0) {
      while (__hip_atomic_load(&flags[(size_t)t * NB + lane], __ATOMIC_RELAXED,
                               __HIP_MEMORY_SCOPE_AGENT) != (unsigned)(t + 1)) {}
      __builtin_amdgcn_fence(__ATOMIC_ACQUIRE, "agent");
      const float* hp = h_buf + (size_t)t * H + lane * SLICE;
      float4 v0 = *(const float4*)(hp + 0);
      float4 v1 = *(const float4*)(hp + 4);
      float4 v2 = *(const float4*)(hp + 8);
      float4 v3 = *(const float4*)(hp + 12);
      *(float4*)&h_lds[lane * SLICE + 0]  = v0;
      *(float4*)&h_lds[lane * SLICE + 4]  = v1;
      *(float4*)&h_lds[lane * SLICE + 8]  = v2;
      *(float4*)&h_lds[lane * SLICE + 12] = v3;
    }
    __syncthreads();

    float4 hf[4];
#pragma unroll
    for (int c = 0; c < 4; ++c)
      hf[c] = *(const float4*)&h_lds[c * 256 + lane * 4];
    const float hprev = h_lds[i_fin];

    // 12 dot-products of length 1024, weights from registers
    float acc[3][4];
#pragma unroll
    for (int g = 0; g < 3; ++g)
#pragma unroll
      for (int o = 0; o < 4; ++o) {
        float s = 0.f;
#pragma unroll
        for (int c = 0; c < 4; ++c) {
          s += wf[g][o][c].x * hf[c].x;
          s += wf[g][o][c].y * hf[c].y;
          s += wf[g][o][c].z * hf[c].z;
          s += wf[g][o][c].w * hf[c].w;
        }
        acc[g][o] = s;
      }
    // butterfly-reduce all 12 across the wave (result in every lane)
#pragma unroll
    for (int g = 0; g < 3; ++g)
#pragma unroll
      for (int o = 0; o < 4; ++o) {
        float s = acc[g][o];
#pragma unroll
        for (int m = 1; m < 64; m <<= 1)
          s += __shfl_xor(s, m, 64);
        acc[g][o] = s;
      }

    const float hr = sel4_f(acc[0], oi);
    const float hz = sel4_f(acc[1], oi);
    const float hn = sel4_f(acc[2], oi);
    const float r = sigmoid_f(g_r + hr + bhr);
    const float z = sigmoid_f(g_z + hz + bhz);
    const float n = tanh_f(g_n + r * (hn + bhn));
    const float hnew = (1.f - z) * n + z * hprev;

    if (lane < 4)
      __hip_atomic_store(&h_buf[(size_t)(t + 1) * H + i_fin], hnew,
                         __ATOMIC_RELAXED, __HIP_MEMORY_SCOPE_AGENT);
    __syncthreads();  // all 4 waves' stores drained before flag
    if (tid == 0)
      __hip_atomic_store(&flags[(size_t)(t + 1) * NB + b], (unsigned)(t + 2),
                         __ATOMIC_RELEASE, __HIP_MEMORY_SCOPE_AGENT);
  }

  // ---- heads: out_mean = h @ w_mean^T + b_mean ; out_std likewise ----
  if (wave == 0) {
    while (__hip_atomic_load(&flags[(size_t)SEQ * NB + lane], __ATOMIC_RELAXED,
                             __HIP_MEMORY_SCOPE_AGENT) != (unsigned)(SEQ + 1)) {}
    __builtin_amdgcn_fence(__ATOMIC_ACQUIRE, "agent");
    const float* hp = h_buf + (size_t)SEQ * H + lane * SLICE;
    float4 v0 = *(const float4*)(hp + 0);
    float4 v1 = *(const float4*)(hp + 4);
    float4 v2 = *(const float4*)(hp + 8);
    float4 v3 = *(const float4*)(hp + 12);
    *(float4*)&h_lds[lane * SLICE + 0]  = v0;
    *(float4*)&h_lds[lane * SLICE + 4]  = v1;
    *(float4*)&h_lds[lane * SLICE + 8]  = v2;
    *(float4*)&h_lds[lane * SLICE + 12] = v3;
  }
  __syncthreads();
  float4 hh[4];
#pragma unroll
  for (int c = 0; c < 4; ++c)
    hh[c] = *(const float4*)&h_lds[c * 256 + lane * 4];

  const float* W   = (wave < 2) ? w_mean : w_std;
  const float* bia = (wave < 2) ? b_mean : b_std;
  float* dst = out + ((wave < 2) ? 0 : H);
  const int r0 = b * SLICE + (wave & 1) * 8;  // waves {0,1}: mean rows, {2,3}: std rows
#pragma unroll
  for (int rr = 0; rr < 8; ++rr) {
    const float* row = W + (size_t)(r0 + rr) * H;
    float s = 0.f;
#pragma unroll
    for (int c = 0; c < 4; ++c) {
      float4 wv = *(const float4*)(row + c * 256 + lane * 4);
      s += wv.x * hh[c].x + wv.y * hh[c].y + wv.z * hh[c].z + wv.w * hh[c].w;
    }
#pragma unroll
    for (int m = 1; m < 64; m <<= 1)
      s += __shfl_xor(s, m, 64);
    if (lane == rr) dst[r0 + rr] = s + bia[r0 + rr];
  }
}

// ---------------------------------------------------------------------------
extern "C" void kernel_launch(void* const* d_in, const int* in_sizes, int n_in,
                              void* d_out, int out_size, void* d_ws, size_t ws_size,
                              hipStream_t stream) {
  const int*   tok    = (const int*)d_in[0];
  const float* hidden = (const float*)d_in[1];
  const float* emb    = (const float*)d_in[2];
  const float* w_ih   = (const float*)d_in[3];
  const float* w_hh   = (const float*)d_in[4];
  const float* b_ih   = (const float*)d_in[5];
  const float* b_hh   = (const float*)d_in[6];
  const float* w_mean = (const float*)d_in[7];
  const float* b_mean = (const float*)d_in[8];
  const float* w_std  = (const float*)d_in[9];
  const float* b_std  = (const float*)d_in[10];
  float* out = (float*)d_out;

  float* gi    = (float*)d_ws;
  float* h_buf = gi + GI_F;
  unsigned int* flags = (unsigned int*)(h_buf + HB_F);

  setup_kernel<<<NB, NT, 0, stream>>>(hidden, h_buf, flags);
  gemm_gi<<<dim3(SEQ / 64, H3 / 64), NT, 0, stream>>>(tok, emb, w_ih, b_ih, gi);
  scan_kernel<<<NB, NT, 0, stream>>>(w_hh, b_hh, w_mean, b_mean, w_std, b_std,
                                     gi, h_buf, flags, out);
}

// Round 2
// 7686.820 us; speedup vs baseline: 1.4358x; 1.4358x over previous
//
#include <hip/hip_runtime.h>
#include <hip/hip_bf16.h>

#define H 1024
#define H3 3072
#define SEQ 2048
#define NB 64        // scan workgroups
#define SLICE 16     // h outputs per WG (H / NB)
#define NTS 512      // scan threads (8 waves)
#define NT 256

// workspace layout (floats)
#define GI_F   ((size_t)SEQ * H3)            // gi: 6,291,456 floats
#define HB_F   ((size_t)(SEQ + 1) * H)       // h history (encoded h+2)

typedef float v4f __attribute__((ext_vector_type(4)));

// ---------------------------------------------------------------------------
// setup: h_buf[0] = hidden + 2 (encoded). Rest of h_buf stays ws-poison/zero,
// both of which read as "not ready" (< 0.5).
// ---------------------------------------------------------------------------
__global__ void setup_kernel(const float* __restrict__ hidden,
                             float* __restrict__ h_buf) {
  v4f v = ((const v4f*)hidden)[threadIdx.x];   // 256 * 4 = 1024
  v += 2.0f;
  ((v4f*)h_buf)[threadIdx.x] = v;
}

// ---------------------------------------------------------------------------
// gi[s][j] = b_ih[j] + sum_k emb[tok[s]][k] * w_ih[j][k]
// ---------------------------------------------------------------------------
__global__ __launch_bounds__(NT) void gemm_gi(
    const int* __restrict__ tok, const float* __restrict__ emb,
    const float* __restrict__ w_ih, const float* __restrict__ b_ih,
    float* __restrict__ gi) {
  __shared__ float As[16][64];  // [k][s]
  __shared__ float Bs[16][64];  // [k][j]
  const int s0 = blockIdx.x * 64;
  const int j0 = blockIdx.y * 64;
  const int tid = threadIdx.x;
  const int tr = tid & 15, tc = tid >> 4;
  const int lr = tid >> 2, lc = (tid & 3) << 2;
  const float* arow = emb + (size_t)tok[s0 + lr] * H;
  const float* brow = w_ih + (size_t)(j0 + lr) * H;
  float acc[4][4] = {};
  for (int k0 = 0; k0 < H; k0 += 16) {
    float4 av = *(const float4*)(arow + k0 + lc);
    float4 bv = *(const float4*)(brow + k0 + lc);
    __syncthreads();
    As[lc + 0][lr] = av.x; As[lc + 1][lr] = av.y;
    As[lc + 2][lr] = av.z; As[lc + 3][lr] = av.w;
    Bs[lc + 0][lr] = bv.x; Bs[lc + 1][lr] = bv.y;
    Bs[lc + 2][lr] = bv.z; Bs[lc + 3][lr] = bv.w;
    __syncthreads();
#pragma unroll
    for (int k = 0; k < 16; ++k) {
      float4 a = *(const float4*)&As[k][tr << 2];
      float4 b = *(const float4*)&Bs[k][tc << 2];
      acc[0][0] += a.x * b.x; acc[0][1] += a.x * b.y; acc[0][2] += a.x * b.z; acc[0][3] += a.x * b.w;
      acc[1][0] += a.y * b.x; acc[1][1] += a.y * b.y; acc[1][2] += a.y * b.z; acc[1][3] += a.y * b.w;
      acc[2][0] += a.z * b.x; acc[2][1] += a.z * b.y; acc[2][2] += a.z * b.z; acc[2][3] += a.z * b.w;
      acc[3][0] += a.w * b.x; acc[3][1] += a.w * b.y; acc[3][2] += a.w * b.z; acc[3][3] += a.w * b.w;
    }
  }
#pragma unroll
  for (int mi = 0; mi < 4; ++mi) {
    float4 v;
    v.x = acc[mi][0] + b_ih[j0 + (tc << 2) + 0];
    v.y = acc[mi][1] + b_ih[j0 + (tc << 2) + 1];
    v.z = acc[mi][2] + b_ih[j0 + (tc << 2) + 2];
    v.w = acc[mi][3] + b_ih[j0 + (tc << 2) + 3];
    *(float4*)&gi[(size_t)(s0 + (tr << 2) + mi) * H3 + j0 + (tc << 2)] = v;
  }
}

// ---------------------------------------------------------------------------
// persistent GRU scan: data-as-flag synchronization
// ---------------------------------------------------------------------------
__device__ __forceinline__ float sigmoid_f(float x) {
  return 1.0f / (1.0f + __expf(-x));
}
__device__ __forceinline__ float tanh_f(float x) {
  return 2.0f / (1.0f + __expf(-2.0f * x)) - 1.0f;  // saturates correctly
}

// 64B L3-coherent load; waitcnt inside the asm so results are valid on exit.
__device__ __forceinline__ void ld_slice_dev(const float* p, v4f& a, v4f& b,
                                             v4f& c, v4f& d) {
  asm volatile(
      "global_load_dwordx4 %0, %4, off sc0 sc1\n\t"
      "global_load_dwordx4 %1, %4, off offset:16 sc0 sc1\n\t"
      "global_load_dwordx4 %2, %4, off offset:32 sc0 sc1\n\t"
      "global_load_dwordx4 %3, %4, off offset:48 sc0 sc1\n\t"
      "s_waitcnt vmcnt(0)"
      : "=v"(a), "=v"(b), "=v"(c), "=v"(d)
      : "v"(p)
      : "memory");
}

__device__ __forceinline__ float min4(v4f v) {
  return fminf(fminf(v.x, v.y), fminf(v.z, v.w));
}

__global__ __launch_bounds__(NTS, 1) void scan_kernel(
    const float* __restrict__ w_hh, const float* __restrict__ b_hh,
    const float* __restrict__ w_mean, const float* __restrict__ b_mean,
    const float* __restrict__ w_std, const float* __restrict__ b_std,
    const float* __restrict__ gi, float* __restrict__ h_buf,
    float* __restrict__ out) {
  __shared__ float h_lds[2][H];
  const int b = blockIdx.x;
  const int tid = threadIdx.x;
  const int wave = tid >> 6;         // 0..7
  const int lane = tid & 63;
  const int oi = lane & 1;
  const int i_base = b * SLICE + wave * 2;   // this wave's 2 outputs
  const int i_fin = i_base + oi;

  // --- w_hh rows for this wave, resident in VGPRs (96 VGPRs/lane) ---
  // wf[g][o][c] = w_hh[g*H + i_base+o][c*256 + lane*4 .. +3]
  v4f wf[3][2][4];
#pragma unroll
  for (int g = 0; g < 3; ++g)
#pragma unroll
    for (int o = 0; o < 2; ++o) {
      const float* row = w_hh + (size_t)(g * H + i_base + o) * H;
#pragma unroll
      for (int c = 0; c < 4; ++c)
        wf[g][o][c] = *(const v4f*)(row + c * 256 + (lane << 2));
    }
  const float bhr = b_hh[i_fin];
  const float bhz = b_hh[H + i_fin];
  const float bhn = b_hh[2 * H + i_fin];

  for (int t = 0; t < SEQ; ++t) {
    const int buf = t & 1;
    // issue gi loads early (latency hidden behind poll / barrier wait)
    const size_t gbase = (size_t)t * H3;
    const float g_r = gi[gbase + i_fin];
    const float g_z = gi[gbase + H + i_fin];
    const float g_n = gi[gbase + 2 * H + i_fin];

    if (wave == 0) {
      // poll the data itself: encoded h in (1,3); poison/zero < 0.5
      const float* hp = h_buf + (size_t)t * H + lane * SLICE;
      v4f v0, v1, v2, v3;
      for (;;) {
        ld_slice_dev(hp, v0, v1, v2, v3);
        float m = fminf(fminf(min4(v0), min4(v1)), fminf(min4(v2), min4(v3)));
        if (__ballot(m > 0.5f) == ~0ull) break;
      }
      // decode and stage. Safe to write before the barrier: poll success
      // proves every sibling wave has stored h[t], hence finished reading
      // this buffer (last used at step t-2).
      float* dst = &h_lds[buf][lane * SLICE];
      *(v4f*)(dst + 0)  = v0 - 2.0f;
      *(v4f*)(dst + 4)  = v1 - 2.0f;
      *(v4f*)(dst + 8)  = v2 - 2.0f;
      *(v4f*)(dst + 12) = v3 - 2.0f;
    }
    __syncthreads();

    v4f hf[4];
#pragma unroll
    for (int c = 0; c < 4; ++c)
      hf[c] = *(const v4f*)&h_lds[buf][c * 256 + (lane << 2)];
    const float hprev = h_lds[buf][i_fin];

    // 6 dot-products of length 1024, weights from registers
    float acc[3][2];
#pragma unroll
    for (int g = 0; g < 3; ++g)
#pragma unroll
      for (int o = 0; o < 2; ++o) {
        float s = 0.f;
#pragma unroll
        for (int c = 0; c < 4; ++c) {
          v4f p = wf[g][o][c] * hf[c];
          s += (p.x + p.y) + (p.z + p.w);
        }
        acc[g][o] = s;
      }
#pragma unroll
    for (int g = 0; g < 3; ++g)
#pragma unroll
      for (int o = 0; o < 2; ++o) {
        float s = acc[g][o];
#pragma unroll
        for (int m = 1; m < 64; m <<= 1)
          s += __shfl_xor(s, m, 64);
        acc[g][o] = s;
      }

    const float hr = oi ? acc[0][1] : acc[0][0];
    const float hz = oi ? acc[1][1] : acc[1][0];
    const float hn = oi ? acc[2][1] : acc[2][0];
    const float r = sigmoid_f(g_r + hr + bhr);
    const float z = sigmoid_f(g_z + hz + bhz);
    const float n = tanh_f(g_n + r * (hn + bhn));
    const float hnew = (1.f - z) * n + z * hprev;

    if (lane < 2)
      __hip_atomic_store(&h_buf[(size_t)(t + 1) * H + i_base + lane],
                         hnew + 2.0f, __ATOMIC_RELAXED,
                         __HIP_MEMORY_SCOPE_AGENT);
    // no trailing barrier: next iteration's poll is the ordering proof
  }

  // ---- heads: out_mean = h @ w_mean^T + b_mean ; out_std likewise ----
  if (wave == 0) {
    const float* hp = h_buf + (size_t)SEQ * H + lane * SLICE;
    v4f v0, v1, v2, v3;
    for (;;) {
      ld_slice_dev(hp, v0, v1, v2, v3);
      float m = fminf(fminf(min4(v0), min4(v1)), fminf(min4(v2), min4(v3)));
      if (__ballot(m > 0.5f) == ~0ull) break;
    }
    float* dst = &h_lds[0][lane * SLICE];
    *(v4f*)(dst + 0)  = v0 - 2.0f;
    *(v4f*)(dst + 4)  = v1 - 2.0f;
    *(v4f*)(dst + 8)  = v2 - 2.0f;
    *(v4f*)(dst + 12) = v3 - 2.0f;
  }
  __syncthreads();
  v4f hh[4];
#pragma unroll
  for (int c = 0; c < 4; ++c)
    hh[c] = *(const v4f*)&h_lds[0][c * 256 + (lane << 2)];

  // 8 waves: waves 0-3 -> mean rows, 4-7 -> std rows; 4 rows per wave
  const float* W   = (wave < 4) ? w_mean : w_std;
  const float* bia = (wave < 4) ? b_mean : b_std;
  float* dst = out + ((wave < 4) ? 0 : H);
  const int r0 = b * SLICE + (wave & 3) * 4;
#pragma unroll
  for (int rr = 0; rr < 4; ++rr) {
    const float* row = W + (size_t)(r0 + rr) * H;
    float s = 0.f;
#pragma unroll
    for (int c = 0; c < 4; ++c) {
      v4f wv = *(const v4f*)(row + c * 256 + (lane << 2));
      v4f p = wv * hh[c];
      s += (p.x + p.y) + (p.z + p.w);
    }
#pragma unroll
    for (int m = 1; m < 64; m <<= 1)
      s += __shfl_xor(s, m, 64);
    if (lane == rr) dst[r0 + rr] = s + bia[r0 + rr];
  }
}

// ---------------------------------------------------------------------------
extern "C" void kernel_launch(void* const* d_in, const int* in_sizes, int n_in,
                              void* d_out, int out_size, void* d_ws, size_t ws_size,
                              hipStream_t stream) {
  const int*   tok    = (const int*)d_in[0];
  const float* hidden = (const float*)d_in[1];
  const float* emb    = (const float*)d_in[2];
  const float* w_ih   = (const float*)d_in[3];
  const float* w_hh   = (const float*)d_in[4];
  const float* b_ih   = (const float*)d_in[5];
  const float* b_hh   = (const float*)d_in[6];
  const float* w_mean = (const float*)d_in[7];
  const float* b_mean = (const float*)d_in[8];
  const float* w_std  = (const float*)d_in[9];
  const float* b_std  = (const float*)d_in[10];
  float* out = (float*)d_out;

  float* gi    = (float*)d_ws;
  float* h_buf = gi + GI_F;

  setup_kernel<<<1, NT, 0, stream>>>(hidden, h_buf);
  gemm_gi<<<dim3(SEQ / 64, H3 / 64), NT, 0, stream>>>(tok, emb, w_ih, b_ih, gi);
  scan_kernel<<<NB, NTS, 0, stream>>>(w_hh, b_hh, w_mean, b_mean, w_std, b_std,
                                      gi, h_buf, out);
}

// Round 3
// 7483.194 us; speedup vs baseline: 1.4749x; 1.0272x over previous
//
#include <hip/hip_runtime.h>
#include <hip/hip_bf16.h>

#define H 1024
#define H3 3072
#define SEQ 2048
#define NB 64        // scan workgroups
#define SLICE 16     // h outputs per WG (H / NB)
#define NTS 512      // scan threads (8 waves)
#define NT 256

// workspace layout (floats)
#define GI_F ((size_t)SEQ * H3)              // gi: 6,291,456 floats

typedef float v4f __attribute__((ext_vector_type(4)));

// Pin a value as asm-defined: compiler cannot rematerialize it by reloading
// from global memory; with VGPR budget 256 (512-thr WG @ min 1 wave/EU) it
// stays register-resident instead of spilling.
#define KEEP(x) asm volatile("" : "+v"(x))

// ---------------------------------------------------------------------------
// setup: h_buf[0] = hidden + 2 (encoded, range (1,3)). Rest of h_buf is
// ws-poison 0xAA.. = -3e-13, which reads as "not ready" (< 0.5).
// ---------------------------------------------------------------------------
__global__ void setup_kernel(const float* __restrict__ hidden,
                             float* __restrict__ h_buf) {
  v4f v = ((const v4f*)hidden)[threadIdx.x];   // 256 * 4 = 1024
  v += 2.0f;
  ((v4f*)h_buf)[threadIdx.x] = v;
}

// ---------------------------------------------------------------------------
// gi[s][j] = b_ih[j] + sum_k emb[tok[s]][k] * w_ih[j][k]
// ---------------------------------------------------------------------------
__global__ __launch_bounds__(NT) void gemm_gi(
    const int* __restrict__ tok, const float* __restrict__ emb,
    const float* __restrict__ w_ih, const float* __restrict__ b_ih,
    float* __restrict__ gi) {
  __shared__ float As[16][64];  // [k][s]
  __shared__ float Bs[16][64];  // [k][j]
  const int s0 = blockIdx.x * 64;
  const int j0 = blockIdx.y * 64;
  const int tid = threadIdx.x;
  const int tr = tid & 15, tc = tid >> 4;
  const int lr = tid >> 2, lc = (tid & 3) << 2;
  const float* arow = emb + (size_t)tok[s0 + lr] * H;
  const float* brow = w_ih + (size_t)(j0 + lr) * H;
  float acc[4][4] = {};
  for (int k0 = 0; k0 < H; k0 += 16) {
    float4 av = *(const float4*)(arow + k0 + lc);
    float4 bv = *(const float4*)(brow + k0 + lc);
    __syncthreads();
    As[lc + 0][lr] = av.x; As[lc + 1][lr] = av.y;
    As[lc + 2][lr] = av.z; As[lc + 3][lr] = av.w;
    Bs[lc + 0][lr] = bv.x; Bs[lc + 1][lr] = bv.y;
    Bs[lc + 2][lr] = bv.z; Bs[lc + 3][lr] = bv.w;
    __syncthreads();
#pragma unroll
    for (int k = 0; k < 16; ++k) {
      float4 a = *(const float4*)&As[k][tr << 2];
      float4 b = *(const float4*)&Bs[k][tc << 2];
      acc[0][0] += a.x * b.x; acc[0][1] += a.x * b.y; acc[0][2] += a.x * b.z; acc[0][3] += a.x * b.w;
      acc[1][0] += a.y * b.x; acc[1][1] += a.y * b.y; acc[1][2] += a.y * b.z; acc[1][3] += a.y * b.w;
      acc[2][0] += a.z * b.x; acc[2][1] += a.z * b.y; acc[2][2] += a.z * b.z; acc[2][3] += a.z * b.w;
      acc[3][0] += a.w * b.x; acc[3][1] += a.w * b.y; acc[3][2] += a.w * b.z; acc[3][3] += a.w * b.w;
    }
  }
#pragma unroll
  for (int mi = 0; mi < 4; ++mi) {
    float4 v;
    v.x = acc[mi][0] + b_ih[j0 + (tc << 2) + 0];
    v.y = acc[mi][1] + b_ih[j0 + (tc << 2) + 1];
    v.z = acc[mi][2] + b_ih[j0 + (tc << 2) + 2];
    v.w = acc[mi][3] + b_ih[j0 + (tc << 2) + 3];
    *(float4*)&gi[(size_t)(s0 + (tr << 2) + mi) * H3 + j0 + (tc << 2)] = v;
  }
}

// ---------------------------------------------------------------------------
// persistent GRU scan: data-as-flag sync, barrier-free, LDS-free
// ---------------------------------------------------------------------------
__device__ __forceinline__ float sigmoid_f(float x) {
  return 1.0f / (1.0f + __expf(-x));
}
__device__ __forceinline__ float tanh_f(float x) {
  return 2.0f / (1.0f + __expf(-2.0f * x)) - 1.0f;  // saturates correctly
}
__device__ __forceinline__ float min4(v4f v) {
  return fminf(fminf(v.x, v.y), fminf(v.z, v.w));
}

// Load this lane's 16 h values (4 chunks, 1024B apart) L3-coherently.
__device__ __forceinline__ void ld_h(const float* p, v4f& a, v4f& b,
                                     v4f& c, v4f& d) {
  asm volatile(
      "global_load_dwordx4 %0, %4, off sc0 sc1\n\t"
      "global_load_dwordx4 %1, %4, off offset:1024 sc0 sc1\n\t"
      "global_load_dwordx4 %2, %4, off offset:2048 sc0 sc1\n\t"
      "global_load_dwordx4 %3, %4, off offset:3072 sc0 sc1\n\t"
      "s_waitcnt vmcnt(0)"
      : "=v"(a), "=v"(b), "=v"(c), "=v"(d)
      : "v"(p)
      : "memory");
}

__global__ __launch_bounds__(NTS, 1) void scan_kernel(
    const float* __restrict__ w_hh, const float* __restrict__ b_hh,
    const float* __restrict__ w_mean, const float* __restrict__ b_mean,
    const float* __restrict__ w_std, const float* __restrict__ b_std,
    const float* __restrict__ gi, float* __restrict__ h_buf,
    const float* __restrict__ hidden, float* __restrict__ out) {
  const int b = blockIdx.x;
  const int tid = threadIdx.x;
  const int wave = tid >> 6;         // 0..7
  const int lane = tid & 63;
  const int oi = lane & 1;
  const int i_base = b * SLICE + wave * 2;   // this wave's 2 outputs
  const int i_fin = i_base + oi;

  // --- w_hh rows for this wave, resident in VGPRs (96 VGPRs/lane) ---
  // wf[g][o][c] = w_hh[g*H + i_base+o][c*256 + lane*4 .. +3]
  v4f wf[3][2][4];
#pragma unroll
  for (int g = 0; g < 3; ++g)
#pragma unroll
    for (int o = 0; o < 2; ++o) {
      const float* row = w_hh + (size_t)(g * H + i_base + o) * H;
#pragma unroll
      for (int c = 0; c < 4; ++c)
        wf[g][o][c] = *(const v4f*)(row + c * 256 + (lane << 2));
    }
#pragma unroll
  for (int g = 0; g < 3; ++g)
#pragma unroll
    for (int o = 0; o < 2; ++o)
#pragma unroll
      for (int c = 0; c < 4; ++c)
        KEEP(wf[g][o][c]);

  const float bhr = b_hh[i_fin];
  const float bhz = b_hh[H + i_fin];
  const float bhn = b_hh[2 * H + i_fin];

  // in-register h_prev for this lane's parity output (no LDS round-trip)
  float hprev = hidden[i_fin];

  for (int t = 0; t < SEQ; ++t) {
    // gi loads issued first; their latency overlaps the h poll
    const size_t gbase = (size_t)t * H3;
    const float g_r = gi[gbase + i_fin];
    const float g_z = gi[gbase + H + i_fin];
    const float g_n = gi[gbase + 2 * H + i_fin];

    // every wave direct-polls h[t] into registers (encoded in (1,3))
    const float* hp = h_buf + (size_t)t * H + (lane << 2);
    v4f h0, h1, h2, h3;
    for (;;) {
      ld_h(hp, h0, h1, h2, h3);
      float m = fminf(fminf(min4(h0), min4(h1)), fminf(min4(h2), min4(h3)));
      if (__ballot(m > 0.5f) == ~0ull) break;
    }
    h0 -= 2.0f; h1 -= 2.0f; h2 -= 2.0f; h3 -= 2.0f;

    // 6 dot-products of length 1024, weights from registers
    float acc[3][2];
#pragma unroll
    for (int g = 0; g < 3; ++g)
#pragma unroll
      for (int o = 0; o < 2; ++o) {
        v4f p = wf[g][o][0] * h0;
        p += wf[g][o][1] * h1;
        p += wf[g][o][2] * h2;
        p += wf[g][o][3] * h3;
        acc[g][o] = (p.x + p.y) + (p.z + p.w);
      }
#pragma unroll
    for (int g = 0; g < 3; ++g)
#pragma unroll
      for (int o = 0; o < 2; ++o) {
        float s = acc[g][o];
#pragma unroll
        for (int m = 1; m < 64; m <<= 1)
          s += __shfl_xor(s, m, 64);
        acc[g][o] = s;
      }

    const float hr = oi ? acc[0][1] : acc[0][0];
    const float hz = oi ? acc[1][1] : acc[1][0];
    const float hn = oi ? acc[2][1] : acc[2][0];
    const float r = sigmoid_f(g_r + hr + bhr);
    const float z = sigmoid_f(g_z + hz + bhz);
    const float n = tanh_f(g_n + r * (hn + bhn));
    const float hnew = (1.f - z) * n + z * hprev;
    hprev = hnew;

    if (lane < 2)
      __hip_atomic_store(&h_buf[(size_t)(t + 1) * H + i_base + lane],
                         hnew + 2.0f, __ATOMIC_RELAXED,
                         __HIP_MEMORY_SCOPE_AGENT);
    // no barrier: next iteration's data poll is the ordering proof
  }

  // ---- heads: out_mean = h @ w_mean^T + b_mean ; out_std likewise ----
  {
    const float* hp = h_buf + (size_t)SEQ * H + (lane << 2);
    v4f h0, h1, h2, h3;
    for (;;) {
      ld_h(hp, h0, h1, h2, h3);
      float m = fminf(fminf(min4(h0), min4(h1)), fminf(min4(h2), min4(h3)));
      if (__ballot(m > 0.5f) == ~0ull) break;
    }
    h0 -= 2.0f; h1 -= 2.0f; h2 -= 2.0f; h3 -= 2.0f;

    // waves 0-3: mean rows, 4-7: std rows; 4 rows per wave
    const float* W   = (wave < 4) ? w_mean : w_std;
    const float* bia = (wave < 4) ? b_mean : b_std;
    float* dst = out + ((wave < 4) ? 0 : H);
    const int r0 = b * SLICE + (wave & 3) * 4;
#pragma unroll
    for (int rr = 0; rr < 4; ++rr) {
      const float* row = W + (size_t)(r0 + rr) * H;
      v4f p = *(const v4f*)(row + 0 * 256 + (lane << 2)) * h0;
      p += *(const v4f*)(row + 1 * 256 + (lane << 2)) * h1;
      p += *(const v4f*)(row + 2 * 256 + (lane << 2)) * h2;
      p += *(const v4f*)(row + 3 * 256 + (lane << 2)) * h3;
      float s = (p.x + p.y) + (p.z + p.w);
#pragma unroll
      for (int m = 1; m < 64; m <<= 1)
        s += __shfl_xor(s, m, 64);
      if (lane == rr) dst[r0 + rr] = s + bia[r0 + rr];
    }
  }
}

// ---------------------------------------------------------------------------
extern "C" void kernel_launch(void* const* d_in, const int* in_sizes, int n_in,
                              void* d_out, int out_size, void* d_ws, size_t ws_size,
                              hipStream_t stream) {
  const int*   tok    = (const int*)d_in[0];
  const float* hidden = (const float*)d_in[1];
  const float* emb    = (const float*)d_in[2];
  const float* w_ih   = (const float*)d_in[3];
  const float* w_hh   = (const float*)d_in[4];
  const float* b_ih   = (const float*)d_in[5];
  const float* b_hh   = (const float*)d_in[6];
  const float* w_mean = (const float*)d_in[7];
  const float* b_mean = (const float*)d_in[8];
  const float* w_std  = (const float*)d_in[9];
  const float* b_std  = (const float*)d_in[10];
  float* out = (float*)d_out;

  float* gi    = (float*)d_ws;
  float* h_buf = gi + GI_F;

  setup_kernel<<<1, NT, 0, stream>>>(hidden, h_buf);
  gemm_gi<<<dim3(SEQ / 64, H3 / 64), NT, 0, stream>>>(tok, emb, w_ih, b_ih, gi);
  scan_kernel<<<NB, NTS, 0, stream>>>(w_hh, b_hh, w_mean, b_mean, w_std, b_std,
                                      gi, h_buf, hidden, out);
}

// Round 5
// 5322.219 us; speedup vs baseline: 2.0738x; 1.4060x over previous
//
#include <hip/hip_runtime.h>
#include <hip/hip_bf16.h>

#define H 1024
#define H3 3072
#define SEQ 2048
#define NB 64        // scan workgroups
#define SLICE 16     // h outputs per WG (H / NB)
#define NTS 512      // scan threads (8 waves)
#define NT 256

// workspace layout (floats)
#define GI_F ((size_t)SEQ * H3)              // gi: 6,291,456 floats

typedef float v4f __attribute__((ext_vector_type(4)));

// Pin a value as asm-defined (prevents remat-by-reload; may live in AGPRs).
#define KEEP(x) asm volatile("" : "+v"(x))

// ---------------------------------------------------------------------------
// setup: h_buf[0] = hidden + 2 (encoded, range (1,3)). Rest of h_buf is
// ws-poison 0xAA.. = -3e-13, which reads as "not ready" (< 0.5).
// ---------------------------------------------------------------------------
__global__ void setup_kernel(const float* __restrict__ hidden,
                             float* __restrict__ h_buf) {
  v4f v = ((const v4f*)hidden)[threadIdx.x];   // 256 * 4 = 1024
  v += 2.0f;
  ((v4f*)h_buf)[threadIdx.x] = v;
}

// ---------------------------------------------------------------------------
// gi[s][j] = b_ih[j] + sum_k emb[tok[s]][k] * w_ih[j][k]
// ---------------------------------------------------------------------------
__global__ __launch_bounds__(NT) void gemm_gi(
    const int* __restrict__ tok, const float* __restrict__ emb,
    const float* __restrict__ w_ih, const float* __restrict__ b_ih,
    float* __restrict__ gi) {
  __shared__ float As[16][64];  // [k][s]
  __shared__ float Bs[16][64];  // [k][j]
  const int s0 = blockIdx.x * 64;
  const int j0 = blockIdx.y * 64;
  const int tid = threadIdx.x;
  const int tr = tid & 15, tc = tid >> 4;
  const int lr = tid >> 2, lc = (tid & 3) << 2;
  const float* arow = emb + (size_t)tok[s0 + lr] * H;
  const float* brow = w_ih + (size_t)(j0 + lr) * H;
  float acc[4][4] = {};
  for (int k0 = 0; k0 < H; k0 += 16) {
    float4 av = *(const float4*)(arow + k0 + lc);
    float4 bv = *(const float4*)(brow + k0 + lc);
    __syncthreads();
    As[lc + 0][lr] = av.x; As[lc + 1][lr] = av.y;
    As[lc + 2][lr] = av.z; As[lc + 3][lr] = av.w;
    Bs[lc + 0][lr] = bv.x; Bs[lc + 1][lr] = bv.y;
    Bs[lc + 2][lr] = bv.z; Bs[lc + 3][lr] = bv.w;
    __syncthreads();
#pragma unroll
    for (int k = 0; k < 16; ++k) {
      float4 a = *(const float4*)&As[k][tr << 2];
      float4 b = *(const float4*)&Bs[k][tc << 2];
      acc[0][0] += a.x * b.x; acc[0][1] += a.x * b.y; acc[0][2] += a.x * b.z; acc[0][3] += a.x * b.w;
      acc[1][0] += a.y * b.x; acc[1][1] += a.y * b.y; acc[1][2] += a.y * b.z; acc[1][3] += a.y * b.w;
      acc[2][0] += a.z * b.x; acc[2][1] += a.z * b.y; acc[2][2] += a.z * b.z; acc[2][3] += a.z * b.w;
      acc[3][0] += a.w * b.x; acc[3][1] += a.w * b.y; acc[3][2] += a.w * b.z; acc[3][3] += a.w * b.w;
    }
  }
#pragma unroll
  for (int mi = 0; mi < 4; ++mi) {
    float4 v;
    v.x = acc[mi][0] + b_ih[j0 + (tc << 2) + 0];
    v.y = acc[mi][1] + b_ih[j0 + (tc << 2) + 1];
    v.z = acc[mi][2] + b_ih[j0 + (tc << 2) + 2];
    v.w = acc[mi][3] + b_ih[j0 + (tc << 2) + 3];
    *(float4*)&gi[(size_t)(s0 + (tr << 2) + mi) * H3 + j0 + (tc << 2)] = v;
  }
}

// ---------------------------------------------------------------------------
// persistent GRU scan: data-as-flag sync, single-wave poll, aggregated store
// ---------------------------------------------------------------------------
__device__ __forceinline__ float sigmoid_f(float x) {
  return 1.0f / (1.0f + __expf(-x));
}
__device__ __forceinline__ float tanh_f(float x) {
  return 2.0f / (1.0f + __expf(-2.0f * x)) - 1.0f;  // saturates correctly
}
__device__ __forceinline__ float min4(v4f v) {
  return fminf(fminf(v.x, v.y), fminf(v.z, v.w));
}

// Load this lane's 4 chunks of h (16B each, 1024B apart = full 4KB vector
// across 64 lanes), L3-coherent, drained.
__device__ __forceinline__ void ld_h(const float* p, v4f& a, v4f& b,
                                     v4f& c, v4f& d) {
  asm volatile(
      "global_load_dwordx4 %0, %4, off sc0 sc1\n\t"
      "global_load_dwordx4 %1, %4, off offset:1024 sc0 sc1\n\t"
      "global_load_dwordx4 %2, %4, off offset:2048 sc0 sc1\n\t"
      "global_load_dwordx4 %3, %4, off offset:3072 sc0 sc1\n\t"
      "s_waitcnt vmcnt(0)"
      : "=v"(a), "=v"(b), "=v"(c), "=v"(d)
      : "v"(p)
      : "memory");
}

__global__ __launch_bounds__(NTS, 1) void scan_kernel(
    const float* __restrict__ w_hh, const float* __restrict__ b_hh,
    const float* __restrict__ w_mean, const float* __restrict__ b_mean,
    const float* __restrict__ w_std, const float* __restrict__ b_std,
    const float* __restrict__ gi, float* __restrict__ h_buf,
    const float* __restrict__ hidden, float* __restrict__ out) {
  __shared__ float h_lds[2][H];
  __shared__ float gather[SLICE];
  const int b = blockIdx.x;
  const int tid = threadIdx.x;
  const int wave = tid >> 6;         // 0..7
  const int lane = tid & 63;
  const int oi = lane & 1;
  const int i_base = b * SLICE + wave * 2;   // this wave's 2 outputs
  const int i_fin = i_base + oi;

  // --- w_hh rows for this wave, register-file resident ---
  v4f wf[3][2][4];
#pragma unroll
  for (int g = 0; g < 3; ++g)
#pragma unroll
    for (int o = 0; o < 2; ++o) {
      const float* row = w_hh + (size_t)(g * H + i_base + o) * H;
#pragma unroll
      for (int c = 0; c < 4; ++c)
        wf[g][o][c] = *(const v4f*)(row + c * 256 + (lane << 2));
    }
#pragma unroll
  for (int g = 0; g < 3; ++g)
#pragma unroll
    for (int o = 0; o < 2; ++o)
#pragma unroll
      for (int c = 0; c < 4; ++c)
        KEEP(wf[g][o][c]);

  const float bhr = b_hh[i_fin];
  const float bhz = b_hh[H + i_fin];
  const float bhn = b_hh[2 * H + i_fin];

  // in-register h_prev for this lane's parity output
  float hprev = hidden[i_fin];

  for (int t = 0; t < SEQ; ++t) {
    const int buf = t & 1;
    // gi loads issued first; latency overlaps the poll / barrier wait
    const size_t gbase = (size_t)t * H3;
    const float g_r = gi[gbase + i_fin];
    const float g_z = gi[gbase + H + i_fin];
    const float g_n = gi[gbase + 2 * H + i_fin];

    if (wave == 0) {
      // wave 0 polls the FULL 4KB h[t]: 4 chunks x 16B per lane
      const float* hp = h_buf + (size_t)t * H + (lane << 2);
      v4f v0, v1, v2, v3;
      for (;;) {
        ld_h(hp, v0, v1, v2, v3);
        float m = fminf(fminf(min4(v0), min4(v1)), fminf(min4(v2), min4(v3)));
        if (__ballot(m > 0.5f) == ~0ull) break;
      }
      float* dst = &h_lds[buf][lane << 2];
      *(v4f*)(dst + 0 * 256) = v0 - 2.0f;
      *(v4f*)(dst + 1 * 256) = v1 - 2.0f;
      *(v4f*)(dst + 2 * 256) = v2 - 2.0f;
      *(v4f*)(dst + 3 * 256) = v3 - 2.0f;
    }
    __syncthreads();  // A: h[t] staged

    v4f hf[4];
#pragma unroll
    for (int c = 0; c < 4; ++c)
      hf[c] = *(const v4f*)&h_lds[buf][c * 256 + (lane << 2)];

    // 6 dot-products of length 1024, weights from register file
    float acc[3][2];
#pragma unroll
    for (int g = 0; g < 3; ++g)
#pragma unroll
      for (int o = 0; o < 2; ++o) {
        v4f p = wf[g][o][0] * hf[0];
        p += wf[g][o][1] * hf[1];
        p += wf[g][o][2] * hf[2];
        p += wf[g][o][3] * hf[3];
        acc[g][o] = (p.x + p.y) + (p.z + p.w);
      }
#pragma unroll
    for (int g = 0; g < 3; ++g)
#pragma unroll
      for (int o = 0; o < 2; ++o) {
        float s = acc[g][o];
#pragma unroll
        for (int m = 1; m < 64; m <<= 1)
          s += __shfl_xor(s, m, 64);
        acc[g][o] = s;
      }

    const float hr = oi ? acc[0][1] : acc[0][0];
    const float hz = oi ? acc[1][1] : acc[1][0];
    const float hn = oi ? acc[2][1] : acc[2][0];
    const float r = sigmoid_f(g_r + hr + bhr);
    const float z = sigmoid_f(g_z + hz + bhz);
    const float n = tanh_f(g_n + r * (hn + bhn));
    const float hnew = (1.f - z) * n + z * hprev;
    hprev = hnew;

    // gather the WG's 16 outputs in LDS, then ONE coalesced 64B store
    if (lane < 2) gather[wave * 2 + lane] = hnew + 2.0f;
    __syncthreads();  // B: gather complete
    if (tid < SLICE)
      __hip_atomic_store(&h_buf[(size_t)(t + 1) * H + b * SLICE + tid],
                         gather[tid], __ATOMIC_RELAXED,
                         __HIP_MEMORY_SCOPE_AGENT);
  }

  // ---- heads: out_mean = h @ w_mean^T + b_mean ; out_std likewise ----
  if (wave == 0) {
    const float* hp = h_buf + (size_t)SEQ * H + (lane << 2);
    v4f v0, v1, v2, v3;
    for (;;) {
      ld_h(hp, v0, v1, v2, v3);
      float m = fminf(fminf(min4(v0), min4(v1)), fminf(min4(v2), min4(v3)));
      if (__ballot(m > 0.5f) == ~0ull) break;
    }
    float* dst = &h_lds[0][lane << 2];
    *(v4f*)(dst + 0 * 256) = v0 - 2.0f;
    *(v4f*)(dst + 1 * 256) = v1 - 2.0f;
    *(v4f*)(dst + 2 * 256) = v2 - 2.0f;
    *(v4f*)(dst + 3 * 256) = v3 - 2.0f;
  }
  __syncthreads();
  v4f hh[4];
#pragma unroll
  for (int c = 0; c < 4; ++c)
    hh[c] = *(const v4f*)&h_lds[0][c * 256 + (lane << 2)];

  // waves 0-3: mean rows, 4-7: std rows; 4 rows per wave
  const float* W   = (wave < 4) ? w_mean : w_std;
  const float* bia = (wave < 4) ? b_mean : b_std;
  float* dst = out + ((wave < 4) ? 0 : H);
  const int r0 = b * SLICE + (wave & 3) * 4;
#pragma unroll
  for (int rr = 0; rr < 4; ++rr) {
    const float* row = W + (size_t)(r0 + rr) * H;
    v4f p = *(const v4f*)(row + 0 * 256 + (lane << 2)) * hh[0];
    p += *(const v4f*)(row + 1 * 256 + (lane << 2)) * hh[1];
    p += *(const v4f*)(row + 2 * 256 + (lane << 2)) * hh[2];
    p += *(const v4f*)(row + 3 * 256 + (lane << 2)) * hh[3];
    float s = (p.x + p.y) + (p.z + p.w);
#pragma unroll
    for (int m = 1; m < 64; m <<= 1)
      s += __shfl_xor(s, m, 64);
    if (lane == rr) dst[r0 + rr] = s + bia[r0 + rr];
  }
}

// ---------------------------------------------------------------------------
extern "C" void kernel_launch(void* const* d_in, const int* in_sizes, int n_in,
                              void* d_out, int out_size, void* d_ws, size_t ws_size,
                              hipStream_t stream) {
  const int*   tok    = (const int*)d_in[0];
  const float* hidden = (const float*)d_in[1];
  const float* emb    = (const float*)d_in[2];
  const float* w_ih   = (const float*)d_in[3];
  const float* w_hh   = (const float*)d_in[4];
  const float* b_ih   = (const float*)d_in[5];
  const float* b_hh   = (const float*)d_in[6];
  const float* w_mean = (const float*)d_in[7];
  const float* b_mean = (const float*)d_in[8];
  const float* w_std  = (const float*)d_in[9];
  const float* b_std  = (const float*)d_in[10];
  float* out = (float*)d_out;

  float* gi    = (float*)d_ws;
  float* h_buf = gi + GI_F;

  setup_kernel<<<1, NT, 0, stream>>>(hidden, h_buf);
  gemm_gi<<<dim3(SEQ / 64, H3 / 64), NT, 0, stream>>>(tok, emb, w_ih, b_ih, gi);
  scan_kernel<<<NB, NTS, 0, stream>>>(w_hh, b_hh, w_mean, b_mean, w_std, b_std,
                                      gi, h_buf, hidden, out);
}